// Round 8
// baseline (95.328 us; speedup 1.0000x reference)
//
#include <hip/hip_runtime.h>
#include <hip/hip_fp16.h>

// NCC (local normalized cross-correlation) loss, 9x9x9 window, zero-pad.
// Volume: [1,1,128,160,192] f32. Output: scalar f32 = 1 - mean(cc).
//
// R8: K1 = fused W-sum + H-sum -> B (half2), halo via __shfl:
//     block = (g, d, hc): g0: I->{ch0,ch2}; g1: J->{ch1,ch3}; g2: IJ->ch4.
//     96 active threads/block (1 per half2 pair), each loads ONLY its own
//     float2 per row; neighbor pairs come from 8 wave shuffles; the
//     wave0/wave1 seam (4 lanes) falls back to direct L1-hot loads.
//     All h-bound branches are block-uniform. H-FIFO as in R6 pass2.
// K2 = R6 pass3: D-axis reload sliding window + cc + atomic reduce.
// finalize: out = 1 - acc/N.
// ws: B 5*N/2 half2 + acc = 39.3 MB.

#define D_ 128
#define H_ 160
#define W_ 192
#define WP_ (W_ / 2)               // 96 half2 pairs per line
#define HW_ (H_ * W_)
#define HWP_ (HW_ / 2)             // half2 per d-slice
#define N_ (D_ * H_ * W_)          // 3,932,160
#define NH2 (N_ / 2)               // half2 per channel
#define WIN_INV (1.0f / 729.0f)
#define HR 20                      // h-run length in K1 (8 chunks)
#define CH3 8                      // d-run length in K2

__device__ __forceinline__ __half2 f2h(float x, float y) {
    return __float22half2_rn(make_float2(x, y));
}
__device__ __forceinline__ float2 h2f(__half2 v) { return __half22float2(v); }

// ------------------- K1: fused W-sum + H-sum -> B ------------------------
__global__ __launch_bounds__(128) void ncc_k1(const float* __restrict__ I,
                                              const float* __restrict__ J,
                                              __half2* __restrict__ B,
                                              float* __restrict__ acc) {
    const int b = blockIdx.x;
    const int tid = threadIdx.x;
    if (b == 0 && tid == 0) *acc = 0.0f;
    if (tid >= WP_) return;                       // 96 active lanes
    const int hc = b & 7;
    const int d  = (b >> 3) & 127;
    const int g  = b >> 10;                       // 0,1,2 (block-uniform)
    const int wp = tid;
    const int lane = tid & 63;
    const int h0 = hc * HR;
    const float* __restrict__ PA = (g == 1 ? J : I) + (size_t)d * HW_;
    const float* __restrict__ PB = J + (size_t)d * HW_;

    const size_t obase = (size_t)d * (H_ * WP_) + wp;
    __half2* out0 = B + (size_t)(g == 0 ? 0 : (g == 1 ? 1 : 4)) * NH2 + obase;
    __half2* out1 = B + (size_t)(g == 0 ? 2 : 3) * NH2 + obase;  // unused g2

    // neighbor pair at wp+dlt of a per-lane float2 stream; seam lanes load.
    auto nbr = [&](float2 v, int dlt, const float* row) -> float2 {
        const int q = wp + dlt;
        const int sl = lane + dlt;
        float2 r;
        r.x = __shfl(v.x, sl & 63, 64);
        r.y = __shfl(v.y, sl & 63, 64);
        if ((unsigned)q >= (unsigned)WP_) {
            r.x = 0.f; r.y = 0.f;                 // W zero-pad
        } else if (sl != (sl & 63)) {
            r = *(const float2*)(row + 2 * q);    // wave seam (<=4 lanes)
        }
        return r;
    };

    // W-window sums (left,right) at row h: o0 = lin (g0/g1) or IJ (g2),
    // o1 = squared stream (g0/g1 only).
    auto rowsum = [&](int h, float2& o0, float2& o1) {
        o0 = make_float2(0.f, 0.f);
        o1 = make_float2(0.f, 0.f);
        if ((unsigned)h >= (unsigned)H_) return;  // block-uniform branch
        const float* ra = PA + h * W_;
        const float2 va = *(const float2*)(ra + 2 * wp);
        const float2 am2 = nbr(va, -2, ra), am1 = nbr(va, -1, ra),
                     ap1 = nbr(va,  1, ra), ap2 = nbr(va,  2, ra);
        if (g == 2) {
            const float* rb = PB + h * W_;
            const float2 vb = *(const float2*)(rb + 2 * wp);
            const float2 bm2 = nbr(vb, -2, rb), bm1 = nbr(vb, -1, rb),
                         bp1 = nbr(vb,  1, rb), bp2 = nbr(vb,  2, rb);
            const float pm2x = am2.x * bm2.x, pm2y = am2.y * bm2.y;
            const float pm1x = am1.x * bm1.x, pm1y = am1.y * bm1.y;
            const float pvx  = va.x  * vb.x,  pvy  = va.y  * vb.y;
            const float pp1x = ap1.x * bp1.x, pp1y = ap1.y * bp1.y;
            const float pp2x = ap2.x * bp2.x, pp2y = ap2.y * bp2.y;
            const float core = pm1x + pm1y + pvx + pvy + pp1x + pp1y;
            o0.x = core + pm2x + pm2y + pp2x;
            o0.y = core + pm2y + pp2x + pp2y;
        } else {
            const float core = am1.x + am1.y + va.x + va.y + ap1.x + ap1.y;
            o0.x = core + am2.x + am2.y + ap2.x;
            o0.y = core + am2.y + ap2.x + ap2.y;
            const float qm2x = am2.x * am2.x, qm2y = am2.y * am2.y;
            const float qm1x = am1.x * am1.x, qm1y = am1.y * am1.y;
            const float qvx  = va.x * va.x,   qvy  = va.y * va.y;
            const float qp1x = ap1.x * ap1.x, qp1y = ap1.y * ap1.y;
            const float qp2x = ap2.x * ap2.x, qp2y = ap2.y * ap2.y;
            const float coreq = qm1x + qm1y + qvx + qvy + qp1x + qp1y;
            o1.x = coreq + qm2x + qm2y + qp2x;
            o1.y = coreq + qm2y + qp2x + qp2y;
        }
    };

    float2 win0[9], win1[9];
    float2 S0 = make_float2(0.f, 0.f), S1 = make_float2(0.f, 0.f);

#pragma unroll
    for (int j = 0; j < 9; ++j) {                 // FIFO warm-up
        float2 o0, o1;
        rowsum(h0 - 4 + j, o0, o1);
        win0[j] = o0; win1[j] = o1;
        S0.x += o0.x; S0.y += o0.y; S1.x += o1.x; S1.y += o1.y;
    }
#pragma unroll
    for (int i = 0; i < HR; ++i) {                // main run
        const int h = h0 + i;
        out0[h * WP_] = f2h(S0.x, S0.y);
        if (g != 2) out1[h * WP_] = f2h(S1.x, S1.y);
        if (i + 1 < HR) {
            float2 o0, o1;
            rowsum(h + 5, o0, o1);
            S0.x += o0.x - win0[0].x; S0.y += o0.y - win0[0].y;
            S1.x += o1.x - win1[0].x; S1.y += o1.y - win1[0].y;
#pragma unroll
            for (int j = 0; j < 8; ++j) { win0[j] = win0[j + 1]; win1[j] = win1[j + 1]; }
            win0[8] = o0; win1[8] = o1;
        }
    }
}

// ---- K2: D-axis box sum + cc + reduce, reload sliding window (R6) --------
__global__ __launch_bounds__(256) void ncc_k2(const __half2* __restrict__ B,
                                              float* __restrict__ acc) {
    const int pp = (blockIdx.x % (HWP_ / 256)) * 256 + threadIdx.x;
    const int d0 = (blockIdx.x / (HWP_ / 256)) * CH3;
    const __half2* base = B + pp;

    float2 S[5];
    float sum = 0.f;
#pragma unroll
    for (int c = 0; c < 5; ++c) S[c] = make_float2(0.f, 0.f);
#pragma unroll
    for (int j = -4; j <= 4; ++j) {
        int dd = d0 + j;
        if ((unsigned)dd < (unsigned)D_) {
#pragma unroll
            for (int c = 0; c < 5; ++c) {
                float2 v = h2f(base[c * NH2 + dd * HWP_]);
                S[c].x += v.x; S[c].y += v.y;
            }
        }
    }
#pragma unroll
    for (int i = 0; i < CH3; ++i) {
        {
            float cr = S[4].x - S[1].x * S[0].x * WIN_INV;
            float Iv = S[2].x - S[0].x * S[0].x * WIN_INV;
            float Jv = S[3].x - S[1].x * S[1].x * WIN_INV;
            sum += cr * cr / (Iv * Jv + 1e-5f);
        }
        {
            float cr = S[4].y - S[1].y * S[0].y * WIN_INV;
            float Iv = S[2].y - S[0].y * S[0].y * WIN_INV;
            float Jv = S[3].y - S[1].y * S[1].y * WIN_INV;
            sum += cr * cr / (Iv * Jv + 1e-5f);
        }
        if (i + 1 < CH3) {
            int dl = d0 + i + 5;
            int dt = d0 + i - 4;
            if (dl < D_) {
#pragma unroll
                for (int c = 0; c < 5; ++c) {
                    float2 v = h2f(base[c * NH2 + dl * HWP_]);
                    S[c].x += v.x; S[c].y += v.y;
                }
            }
            if (dt >= 0) {
#pragma unroll
                for (int c = 0; c < 5; ++c) {
                    float2 v = h2f(base[c * NH2 + dt * HWP_]);
                    S[c].x -= v.x; S[c].y -= v.y;
                }
            }
        }
    }

    for (int off = 32; off; off >>= 1) sum += __shfl_down(sum, off, 64);
    __shared__ float wsum[4];
    const int lane = threadIdx.x & 63, wv = threadIdx.x >> 6;
    if (lane == 0) wsum[wv] = sum;
    __syncthreads();
    if (threadIdx.x == 0)
        atomicAdd(acc, wsum[0] + wsum[1] + wsum[2] + wsum[3]);
}

__global__ void ncc_finalize(const float* __restrict__ acc,
                             float* __restrict__ out) {
    out[0] = 1.0f - acc[0] * (1.0f / (float)N_);
}

extern "C" void kernel_launch(void* const* d_in, const int* in_sizes, int n_in,
                              void* d_out, int out_size, void* d_ws, size_t ws_size,
                              hipStream_t stream) {
    const float* I = (const float*)d_in[0];   // y_true
    const float* J = (const float*)d_in[1];   // y_pred
    __half2* B = (__half2*)d_ws;               // 5*NH2 half2
    float* acc = (float*)(B + 5 * NH2);
    float* out = (float*)d_out;

    ncc_k1<<<3 * D_ * 8, 128, 0, stream>>>(I, J, B, acc);
    ncc_k2<<<(HWP_ / 256) * (D_ / CH3), 256, 0, stream>>>(B, acc);
    ncc_finalize<<<1, 1, 0, stream>>>(acc, out);
}

// Round 9
// 54.534 us; speedup vs baseline: 1.7480x; 1.7480x over previous
//
#include <hip/hip_runtime.h>
#include <hip/hip_fp16.h>

// NCC (local normalized cross-correlation) loss, 9x9x9 window, zero-pad.
// Volume: [1,1,128,160,192] f32. Output: scalar f32 = 1 - mean(cc).
//
// R9 = R6 structure + channel-PACKED intermediates:
//   per pixel-pair (2 adjacent W pixels), ch0..3 (I,J,I2,J2 box sums) are
//   one uint4 (4x half2, 16B) and ch4 (IJ) one u32 (half2). Every stage
//   moves all 5 channels with 2 memory instructions instead of 5-10.
//   pass1: W-sums -> Aq/As.         (read I,J f32; 2 packed stores)
//   pass2: H-sums Aq/As -> Bq/Bs.   (packed 9-FIFO per thread, runs of 10)
//   pass3: D-sums + cc + reduce.    (packed 9-FIFO, runs of 8, atomicAdd)
//   finalize: out = 1 - acc/N.
// ws: Aq 31.5MB | Bq 31.5MB | As 7.9MB | Bs 7.9MB | acc = 78.6 MB.

#define D_ 128
#define H_ 160
#define W_ 192
#define WP_ (W_ / 2)               // 96 pairs per line
#define HW_ (H_ * W_)
#define HWP_ (HW_ / 2)             // 15360 pairs per d-slice
#define N_ (D_ * H_ * W_)
#define NP_ (N_ / 2)               // 1,966,080 pairs total
#define WIN_INV (1.0f / 729.0f)
#define HR2 10                     // h-run length in pass2 (16 chunks)
#define CH3 8                      // d-run length in pass3 (16 chunks)

__device__ __forceinline__ unsigned pack2(float x, float y) {
    __half2 h = __float22half2_rn(make_float2(x, y));
    return *reinterpret_cast<unsigned*>(&h);
}
__device__ __forceinline__ float2 unpack2(unsigned u) {
    __half2 h = *reinterpret_cast<__half2*>(&u);
    return __half22float2(h);
}

__device__ __forceinline__ void addU(float2 S[5], const uint4& q, unsigned sv) {
    float2 v0 = unpack2(q.x), v1 = unpack2(q.y), v2 = unpack2(q.z),
           v3 = unpack2(q.w), v4 = unpack2(sv);
    S[0].x += v0.x; S[0].y += v0.y;
    S[1].x += v1.x; S[1].y += v1.y;
    S[2].x += v2.x; S[2].y += v2.y;
    S[3].x += v3.x; S[3].y += v3.y;
    S[4].x += v4.x; S[4].y += v4.y;
}
__device__ __forceinline__ void subU(float2 S[5], const uint4& q, unsigned sv) {
    float2 v0 = unpack2(q.x), v1 = unpack2(q.y), v2 = unpack2(q.z),
           v3 = unpack2(q.w), v4 = unpack2(sv);
    S[0].x -= v0.x; S[0].y -= v0.y;
    S[1].x -= v1.x; S[1].y -= v1.y;
    S[2].x -= v2.x; S[2].y -= v2.y;
    S[3].x -= v3.x; S[3].y -= v3.y;
    S[4].x -= v4.x; S[4].y -= v4.y;
}

// ---------------- pass1: W-axis box sum -> packed A ------------------------
__global__ __launch_bounds__(256) void ncc_pass1(const float* __restrict__ I,
                                                 const float* __restrict__ J,
                                                 uint4* __restrict__ Aq,
                                                 unsigned* __restrict__ As,
                                                 float* __restrict__ acc) {
    __shared__ float sI[2 * W_];
    __shared__ float sJ[2 * W_];
    const int t = threadIdx.x;
    const int line0 = blockIdx.x * 2;
    const int base = line0 * W_;
    sI[t] = I[base + t];
    sJ[t] = J[base + t];
    if (t < 2 * W_ - 256) { sI[t + 256] = I[base + t + 256]; sJ[t + 256] = J[base + t + 256]; }
    if (blockIdx.x == 0 && t == 0) *acc = 0.0f;
    __syncthreads();
    if (t >= 2 * WP_) return;
    const int ll = t / WP_;
    const int wp = t % WP_;
    const int w0 = 2 * wp;
    const float* a_ = sI + ll * W_;
    const float* b_ = sJ + ll * W_;
    float s1a = 0, s2a = 0, s3a = 0, s4a = 0, s5a = 0;
    float s1b = 0, s2b = 0, s3b = 0, s4b = 0, s5b = 0;
#pragma unroll
    for (int j = -4; j <= 5; ++j) {
        int idx = w0 + j;
        float a = 0.f, b = 0.f;
        if (idx >= 0 && idx < W_) { a = a_[idx]; b = b_[idx]; }
        float p3 = a * a, p4 = b * b, p5 = a * b;
        if (j <= 4) { s1a += a; s2a += b; s3a += p3; s4a += p4; s5a += p5; }
        if (j >= -3) { s1b += a; s2b += b; s3b += p3; s4b += p4; s5b += p5; }
    }
    const size_t o = (size_t)(line0 + ll) * WP_ + wp;
    Aq[o] = make_uint4(pack2(s1a, s1b), pack2(s2a, s2b),
                       pack2(s3a, s3b), pack2(s4a, s4b));
    As[o] = pack2(s5a, s5b);
}

// ---------------- pass2: H-axis box sum, packed FIFO -----------------------
__global__ __launch_bounds__(256) void ncc_pass2(const uint4* __restrict__ Aq,
                                                 const unsigned* __restrict__ As,
                                                 uint4* __restrict__ Bq,
                                                 unsigned* __restrict__ Bs) {
    const int t = blockIdx.x * 256 + threadIdx.x;   // < 128*16*96 = 196608
    const int wp = t % WP_;
    const int r = t / WP_;
    const int hc = r & 15;
    const int d = r >> 4;
    const size_t cb = (size_t)d * (H_ * WP_) + wp;
    const uint4* aq = Aq + cb;
    const unsigned* as_ = As + cb;
    uint4* bq = Bq + cb;
    unsigned* bs = Bs + cb;
    const int h0 = hc * HR2;

    uint4 fq[9]; unsigned fs[9];
    float2 S[5] = {{0,0},{0,0},{0,0},{0,0},{0,0}};
#pragma unroll
    for (int j = 0; j < 9; ++j) {
        int hh = h0 - 4 + j;
        uint4 q = make_uint4(0u, 0u, 0u, 0u); unsigned sv = 0u;
        if ((unsigned)hh < (unsigned)H_) {
            q = aq[(size_t)hh * WP_]; sv = as_[(size_t)hh * WP_];
        }
        fq[j] = q; fs[j] = sv;
        addU(S, q, sv);
    }
#pragma unroll
    for (int i = 0; i < HR2; ++i) {
        const int h = h0 + i;
        bq[(size_t)h * WP_] = make_uint4(pack2(S[0].x, S[0].y), pack2(S[1].x, S[1].y),
                                         pack2(S[2].x, S[2].y), pack2(S[3].x, S[3].y));
        bs[(size_t)h * WP_] = pack2(S[4].x, S[4].y);
        if (i + 1 < HR2) {
            int hh = h + 5;
            uint4 q = make_uint4(0u, 0u, 0u, 0u); unsigned sv = 0u;
            if (hh < H_) { q = aq[(size_t)hh * WP_]; sv = as_[(size_t)hh * WP_]; }
            subU(S, fq[0], fs[0]);
            addU(S, q, sv);
#pragma unroll
            for (int j = 0; j < 8; ++j) { fq[j] = fq[j + 1]; fs[j] = fs[j + 1]; }
            fq[8] = q; fs[8] = sv;
        }
    }
}

// ------- pass3: D-axis box sum + cc + reduce, packed FIFO ------------------
__global__ __launch_bounds__(256) void ncc_pass3(const uint4* __restrict__ Bq,
                                                 const unsigned* __restrict__ Bs,
                                                 float* __restrict__ acc) {
    const int pp = (blockIdx.x % (HWP_ / 256)) * 256 + threadIdx.x;
    const int d0 = (blockIdx.x / (HWP_ / 256)) * CH3;
    const uint4* bq = Bq + pp;
    const unsigned* bs = Bs + pp;

    uint4 fq[9]; unsigned fs[9];
    float2 S[5] = {{0,0},{0,0},{0,0},{0,0},{0,0}};
#pragma unroll
    for (int j = 0; j < 9; ++j) {
        int dd = d0 - 4 + j;
        uint4 q = make_uint4(0u, 0u, 0u, 0u); unsigned sv = 0u;
        if ((unsigned)dd < (unsigned)D_) {
            q = bq[(size_t)dd * HWP_]; sv = bs[(size_t)dd * HWP_];
        }
        fq[j] = q; fs[j] = sv;
        addU(S, q, sv);
    }
    float sum = 0.f;
#pragma unroll
    for (int i = 0; i < CH3; ++i) {
        {
            float cr = S[4].x - S[1].x * S[0].x * WIN_INV;
            float Iv = S[2].x - S[0].x * S[0].x * WIN_INV;
            float Jv = S[3].x - S[1].x * S[1].x * WIN_INV;
            sum += cr * cr / (Iv * Jv + 1e-5f);
        }
        {
            float cr = S[4].y - S[1].y * S[0].y * WIN_INV;
            float Iv = S[2].y - S[0].y * S[0].y * WIN_INV;
            float Jv = S[3].y - S[1].y * S[1].y * WIN_INV;
            sum += cr * cr / (Iv * Jv + 1e-5f);
        }
        if (i + 1 < CH3) {
            int dl = d0 + i + 5;
            uint4 q = make_uint4(0u, 0u, 0u, 0u); unsigned sv = 0u;
            if (dl < D_) { q = bq[(size_t)dl * HWP_]; sv = bs[(size_t)dl * HWP_]; }
            subU(S, fq[0], fs[0]);
            addU(S, q, sv);
#pragma unroll
            for (int j = 0; j < 8; ++j) { fq[j] = fq[j + 1]; fs[j] = fs[j + 1]; }
            fq[8] = q; fs[8] = sv;
        }
    }

    for (int off = 32; off; off >>= 1) sum += __shfl_down(sum, off, 64);
    __shared__ float wsum[4];
    const int lane = threadIdx.x & 63, wv = threadIdx.x >> 6;
    if (lane == 0) wsum[wv] = sum;
    __syncthreads();
    if (threadIdx.x == 0)
        atomicAdd(acc, wsum[0] + wsum[1] + wsum[2] + wsum[3]);
}

__global__ void ncc_finalize(const float* __restrict__ acc,
                             float* __restrict__ out) {
    out[0] = 1.0f - acc[0] * (1.0f / (float)N_);
}

extern "C" void kernel_launch(void* const* d_in, const int* in_sizes, int n_in,
                              void* d_out, int out_size, void* d_ws, size_t ws_size,
                              hipStream_t stream) {
    const float* I = (const float*)d_in[0];   // y_true
    const float* J = (const float*)d_in[1];   // y_pred
    char* w = (char*)d_ws;
    uint4* Aq = (uint4*)w;                                 // 31.46 MB
    uint4* Bq = (uint4*)(w + (size_t)NP_ * 16);            // 31.46 MB
    unsigned* As = (unsigned*)(w + (size_t)NP_ * 32);      // 7.86 MB
    unsigned* Bs = (unsigned*)(w + (size_t)NP_ * 36);      // 7.86 MB
    float* acc = (float*)(w + (size_t)NP_ * 40);
    float* out = (float*)d_out;

    ncc_pass1<<<D_ * H_ / 2, 256, 0, stream>>>(I, J, Aq, As, acc);
    ncc_pass2<<<(D_ * 16 * WP_) / 256, 256, 0, stream>>>(Aq, As, Bq, Bs);
    ncc_pass3<<<(HWP_ / 256) * (D_ / CH3), 256, 0, stream>>>(Bq, Bs, acc);
    ncc_finalize<<<1, 1, 0, stream>>>(acc, out);
}